// Round 9
// baseline (94.722 us; speedup 1.0000x reference)
//
#include <hip/hip_runtime.h>
#include <stdint.h>

// y[n,i] = relu(b[idx[n],i] + sum_o w[idx[n],i,o] * x[n,o])
// B=8192, 64 models, 256x256 fp32.
//
// R9 = R8 + T14 async-STAGE for the back half. Front unchanged: fused
// compaction (lgkm-only scan barriers), w q0/q1 + x q0/q1 staged f32 via
// global_load_lds quarter-K double buffers. NEW: q2/q3 of BOTH streams are
// loaded into registers at the earliest possible point (w at t0 after the
// w-DMAs; x right after the x-DMAs post-rid) and written to LDS only after
// the buffer frees (B2/B3). Result: zero vmcnt drains after B1 (all back-
// half barriers are lgkm-only), cold refill latency fully overlapped by the
// front half, ~192 KB/block in flight during the scan.
// 256 blocks (64 models x 2 sample-tiles x 2 out-tiles), 1024 thr, 16 waves
// 4x4 grid of 32x32 tiles, XCD-bijective swizzle.

#define N_MODELS 64
#define IN_F     256
#define OUT_F    256
#define BATCH    8192
#define BM       128
#define BN       128

typedef __bf16 bf16x8 __attribute__((ext_vector_type(8)));
typedef float  f32x4  __attribute__((ext_vector_type(4)));
typedef __attribute__((address_space(3))) uint32_t lds_u32;
typedef const __attribute__((address_space(1))) uint32_t glb_u32;

__device__ __forceinline__ void dma16(const void* g, void* l) {
  __builtin_amdgcn_global_load_lds((glb_u32*)g, (lds_u32*)l, 16, 0, 0);
}

// raw block barrier that waits LDS ops only -> in-flight vmem survives
__device__ __forceinline__ void barrier_lds_only() {
  asm volatile("s_waitcnt lgkmcnt(0)" ::: "memory");
  __builtin_amdgcn_s_barrier();
  __builtin_amdgcn_sched_barrier(0);
}

__device__ __forceinline__ bf16x8 pack8(float4 a, float4 b) {
  bf16x8 o;                       // native casts -> v_cvt_pk_bf16_f32
  o[0] = (__bf16)a.x; o[1] = (__bf16)a.y; o[2] = (__bf16)a.z; o[3] = (__bf16)a.w;
  o[4] = (__bf16)b.x; o[5] = (__bf16)b.y; o[6] = (__bf16)b.z; o[7] = (__bf16)b.w;
  return o;
}

__global__ __launch_bounds__(1024) void fused_kernel(
    const float* __restrict__ x, const int* __restrict__ idxs,
    const float* __restrict__ w, const float* __restrict__ bias_g,
    float* __restrict__ out) {
  // XCD-bijective swizzle (256 % 8 == 0): a model's 4 blocks -> one XCD
  const int b     = (blockIdx.x & 7) * 32 + (blockIdx.x >> 3);
  const int model = b >> 2;
  const int s     = (b >> 1) & 1;    // sample-tile (rows s*128 ..)
  const int i0    = (b & 1) * BN;    // out-col tile
  const int t     = threadIdx.x;
  const int lane  = t & 63;
  const int wv    = t >> 6;          // 0..15

  __shared__ float w_lds[2][BM][64];   // w quarter-K f32, dbuf
  __shared__ float x_lds[2][BM][64];   // x quarter-K f32, dbuf
  __shared__ int rid[BM];
  __shared__ int wsum[16];

  const float* wbase = w + (size_t)model * (IN_F * OUT_F) + (size_t)i0 * IN_F;
  const int l_r = lane >> 4;         // row within the 4-row group
  const int l_c = lane & 15;         // 16B chunk within the row
#define W_DMA(q, buf)                                                        \
  {                                                                          \
    _Pragma("unroll")                                                        \
    for (int j = 0; j < 2; ++j) {                                            \
      const int r0 = wv * 8 + j * 4;                                         \
      const int rr = r0 + l_r;                                               \
      const float* gs = wbase + (size_t)rr * IN_F + (q) * 64                 \
                        + ((l_c ^ (rr & 7)) << 2);                           \
      dma16(gs, &w_lds[buf][r0][0]);                                         \
    }                                                                        \
  }
  // reg-prefetch of a w quarter (same lane->element mapping as W_DMA)
#define W_REG(q, dst)                                                        \
  {                                                                          \
    _Pragma("unroll")                                                        \
    for (int j = 0; j < 2; ++j) {                                            \
      const int rr = wv * 8 + j * 4 + l_r;                                   \
      dst[j] = *(const float4*)(wbase + (size_t)rr * IN_F + (q) * 64         \
                                + ((l_c ^ (rr & 7)) << 2));                  \
    }                                                                        \
  }

  // ---- idx loads FIRST (scan critical path; in-order vmcnt) ----
  const int4* ip = (const int4*)idxs + t * 2;   // 8 idxs/thread
  int4 iv0 = ip[0], iv1 = ip[1];

  float4 wr2[2], wr3[2];             // w q2/q3 register prefetch
  // s==0 blocks never early-exit: put all w traffic in flight at t0
  if (s == 0) { W_DMA(0, 0) W_DMA(1, 1) W_REG(2, wr2) W_REG(3, wr3) }

  if (t < BM) rid[t] = -1;

  // ---- compaction: thread t owns idxs[8t .. 8t+7] ----
  int cnt = (iv0.x == model) + (iv0.y == model) + (iv0.z == model) + (iv0.w == model)
          + (iv1.x == model) + (iv1.y == model) + (iv1.z == model) + (iv1.w == model);
  int inc = cnt;
#pragma unroll
  for (int d = 1; d < 64; d <<= 1) {
    int u = __shfl_up(inc, d);
    if (lane >= d) inc += u;
  }
  if (lane == 63) wsum[wv] = inc;
  barrier_lds_only();                // RAW-BAR-1: wsum + rid(-1) committed
  int wpre = 0, total = 0;
#pragma unroll
  for (int j = 0; j < 16; ++j) {
    int sj = wsum[j];
    total += sj;
    if (j < wv) wpre += sj;
  }
  const int start = s * BM;
  if (start >= total) return;        // block-uniform (only s==1 can exit;
                                     // those blocks issued no w traffic)
  if (s == 1) { W_DMA(0, 0) W_DMA(1, 1) W_REG(2, wr2) W_REG(3, wr3) }

  int off = wpre + inc - cnt - start;
  {
    int n0 = t * 8;
    if (iv0.x == model) { if ((unsigned)off < BM) rid[off] = n0 + 0; ++off; }
    if (iv0.y == model) { if ((unsigned)off < BM) rid[off] = n0 + 1; ++off; }
    if (iv0.z == model) { if ((unsigned)off < BM) rid[off] = n0 + 2; ++off; }
    if (iv0.w == model) { if ((unsigned)off < BM) rid[off] = n0 + 3; ++off; }
    if (iv1.x == model) { if ((unsigned)off < BM) rid[off] = n0 + 4; ++off; }
    if (iv1.y == model) { if ((unsigned)off < BM) rid[off] = n0 + 5; ++off; }
    if (iv1.z == model) { if ((unsigned)off < BM) rid[off] = n0 + 6; ++off; }
    if (iv1.w == model) { if ((unsigned)off < BM) rid[off] = n0 + 7; ++off; }
  }
  barrier_lds_only();                // RAW-BAR-2: rid ready (vmem untouched)

  // ---- x: per-lane gathered global src, wave-linear LDS dest ----
  // wave wv covers rows [wv*4, wv*4+4) (group 0) and [64+wv*4, ..) (group 1)
  const int   r_0 = wv * 4 + l_r;
  const int   r_1 = 64 + wv * 4 + l_r;
  const int   sr0 = rid[r_0];
  const int   sr1 = rid[r_1];
  const float* xb0 = x + (size_t)(sr0 < 0 ? 0 : sr0) * IN_F
                       + ((l_c ^ (r_0 & 7)) << 2);
  const float* xb1 = x + (size_t)(sr1 < 0 ? 0 : sr1) * IN_F
                       + ((l_c ^ (r_1 & 7)) << 2);
#define X_DMA(q, buf)                                                        \
  {                                                                          \
    dma16(xb0 + (q) * 64, &x_lds[buf][wv * 4][0]);                           \
    dma16(xb1 + (q) * 64, &x_lds[buf][64 + wv * 4][0]);                      \
  }

  X_DMA(0, 0)                        // x q0+q1 in flight immediately
  X_DMA(1, 1)
  float4 xr2[2], xr3[2];             // x q2/q3 register prefetch
  xr2[0] = *(const float4*)(xb0 + 2 * 64);
  xr2[1] = *(const float4*)(xb1 + 2 * 64);
  xr3[0] = *(const float4*)(xb0 + 3 * 64);
  xr3[1] = *(const float4*)(xb1 + 3 * 64);

  // wave tile coords + bias (issued while vmem flies)
  const int wm   = (wv & 3) * 32;    // 4x4 wave grid of 32x32 tiles
  const int wn   = (wv >> 2) * 32;
  const int col  = lane & 15;
  const int quad = lane >> 4;
  float bv[2];
  const float* bp = bias_g + model * OUT_F + i0 + wn + col;
#pragma unroll
  for (int nt = 0; nt < 2; ++nt) bv[nt] = bp[nt * 16];

  __syncthreads();                   // B1: ONLY vmcnt drain = q0,q1 DMA ready

  f32x4 acc[2][2];                   // bias folded into acc init
#pragma unroll
  for (int mt = 0; mt < 2; ++mt)
#pragma unroll
    for (int nt = 0; nt < 2; ++nt)
      acc[mt][nt] = (f32x4){bv[nt], bv[nt], bv[nt], bv[nt]};

  // one quarter = 2 k-steps; A and B frags both f32+XOR-swizzle+pack8
#define MFMA_QUARTER(buf, ks0)                                               \
  {                                                                          \
    _Pragma("unroll")                                                        \
    for (int kk = 0; kk < 2; ++kk) {                                         \
      const int ch0 = kk * 8 + quad * 2;                                     \
      bf16x8 af[2], bfr[2];                                                  \
      _Pragma("unroll")                                                      \
      for (int mt = 0; mt < 2; ++mt) {                                       \
        const int Ra  = wm + mt * 16 + col;                                  \
        const int swa = Ra & 7;                                              \
        float4 a0 = *(const float4*)&x_lds[buf][Ra][((ch0)     ^ swa) << 2]; \
        float4 a1 = *(const float4*)&x_lds[buf][Ra][((ch0 + 1) ^ swa) << 2]; \
        af[mt] = pack8(a0, a1);                                              \
      }                                                                      \
      _Pragma("unroll")                                                      \
      for (int nt = 0; nt < 2; ++nt) {                                       \
        const int R  = wn + nt * 16 + col;                                   \
        const int sw = R & 7;                                                \
        float4 f0 = *(const float4*)&w_lds[buf][R][((ch0)     ^ sw) << 2];   \
        float4 f1 = *(const float4*)&w_lds[buf][R][((ch0 + 1) ^ sw) << 2];   \
        bfr[nt] = pack8(f0, f1);                                             \
      }                                                                      \
      _Pragma("unroll")                                                      \
      for (int mt = 0; mt < 2; ++mt)                                         \
        _Pragma("unroll")                                                    \
        for (int nt = 0; nt < 2; ++nt)                                       \
          acc[mt][nt] = __builtin_amdgcn_mfma_f32_16x16x32_bf16(             \
              af[mt], bfr[nt], acc[mt][nt], 0, 0, 0);                        \
    }                                                                        \
  }

  // write a reg-prefetched quarter into a freed buffer (dest mapping is
  // byte-identical to the DMA's base + lane*16)
#define WX_WRITE(buf, wreg, xreg)                                            \
  {                                                                          \
    _Pragma("unroll")                                                        \
    for (int j = 0; j < 2; ++j) {                                            \
      const int rrw = wv * 8 + j * 4 + l_r;                                  \
      *(float4*)&w_lds[buf][rrw][l_c * 4] = wreg[j];                         \
    }                                                                        \
    *(float4*)&x_lds[buf][r_0][l_c * 4] = xreg[0];                           \
    *(float4*)&x_lds[buf][r_1][l_c * 4] = xreg[1];                           \
  }

  MFMA_QUARTER(0, 0)                 // q0
  barrier_lds_only();                // B2: buf0 reads done (no vmcnt drain)
  WX_WRITE(0, wr2, xr2)              // q2 -> buf0 (regs long since arrived)
  MFMA_QUARTER(1, 2)                 // q1
  barrier_lds_only();                // B3: buf0 writes visible; buf1 free
  WX_WRITE(1, wr3, xr3)              // q3 -> buf1
  MFMA_QUARTER(0, 4)                 // q2
  barrier_lds_only();                // B4: buf1 writes visible
  MFMA_QUARTER(1, 6)                 // q3

  // ---- epilogue: relu + scatter by sample id ----
#pragma unroll
  for (int mt = 0; mt < 2; ++mt) {
#pragma unroll
    for (int reg = 0; reg < 4; ++reg) {
      const int mm = wm + mt * 16 + quad * 4 + reg;   // C/D: row = quad*4+reg
      const int sle = rid[mm];
      if (sle >= 0) {
        float* orow = out + (size_t)sle * OUT_F + i0 + wn + col;
#pragma unroll
        for (int nt = 0; nt < 2; ++nt)
          orow[nt * 16] = fmaxf(acc[mt][nt][reg], 0.0f);
      }
    }
  }
#undef W_DMA
#undef W_REG
#undef X_DMA
#undef MFMA_QUARTER
#undef WX_WRITE
}

extern "C" void kernel_launch(void* const* d_in, const int* in_sizes, int n_in,
                              void* d_out, int out_size, void* d_ws, size_t ws_size,
                              hipStream_t stream) {
  const float* x    = (const float*)d_in[0];
  const int*   idxs = (const int*)d_in[1];
  const float* w    = (const float*)d_in[2];
  const float* b    = (const float*)d_in[3];
  float* out = (float*)d_out;
  (void)d_ws; (void)ws_size;

  fused_kernel<<<N_MODELS * 4, 1024, 0, stream>>>(x, idxs, w, b, out);
}

// Round 10
// 93.941 us; speedup vs baseline: 1.0083x; 1.0083x over previous
//
#include <hip/hip_runtime.h>
#include <stdint.h>

// y[n,i] = relu(b[idx[n],i] + sum_o w[idx[n],i,o] * x[n,o])
// B=8192, 64 models, 256x256 fp32.
//
// R10 = R9 with the spill fixed: __launch_bounds__(1024, 4).
// R9's WRITE_SIZE counter (33.6MB vs 8.4MB output) showed the compiler
// spilled the q2/q3 register prefetch to scratch: under launch_bounds(1024)
// it allocated for 8 waves/SIMD (<=64 VGPR, 2 blocks/CU) -- an occupancy our
// 129KB LDS forbids (1 block/CU). Declaring min 4 waves/EU raises the VGPR
// cap to 128 so the T14 async-stage registers (~92 VGPR live) stay in RF.
//
// Structure (R8/R9): fused compaction (lgkm-only scan barriers), w+x staged
// f32 via global_load_lds quarter-K double buffers (q0/q1), q2/q3 of both
// streams reg-prefetched at the earliest point and ds_written after B2/B3;
// zero vmcnt drains after B1. 256 blocks (64 models x 2 sample-tiles x
// 2 out-tiles), 1024 thr, 16 waves 4x4 grid of 32x32 tiles, XCD swizzle.

#define N_MODELS 64
#define IN_F     256
#define OUT_F    256
#define BATCH    8192
#define BM       128
#define BN       128

typedef __bf16 bf16x8 __attribute__((ext_vector_type(8)));
typedef float  f32x4  __attribute__((ext_vector_type(4)));
typedef __attribute__((address_space(3))) uint32_t lds_u32;
typedef const __attribute__((address_space(1))) uint32_t glb_u32;

__device__ __forceinline__ void dma16(const void* g, void* l) {
  __builtin_amdgcn_global_load_lds((glb_u32*)g, (lds_u32*)l, 16, 0, 0);
}

// raw block barrier that waits LDS ops only -> in-flight vmem survives
__device__ __forceinline__ void barrier_lds_only() {
  asm volatile("s_waitcnt lgkmcnt(0)" ::: "memory");
  __builtin_amdgcn_s_barrier();
  __builtin_amdgcn_sched_barrier(0);
}

__device__ __forceinline__ bf16x8 pack8(float4 a, float4 b) {
  bf16x8 o;                       // native casts -> v_cvt_pk_bf16_f32
  o[0] = (__bf16)a.x; o[1] = (__bf16)a.y; o[2] = (__bf16)a.z; o[3] = (__bf16)a.w;
  o[4] = (__bf16)b.x; o[5] = (__bf16)b.y; o[6] = (__bf16)b.z; o[7] = (__bf16)b.w;
  return o;
}

__global__ __launch_bounds__(1024, 4) void fused_kernel(
    const float* __restrict__ x, const int* __restrict__ idxs,
    const float* __restrict__ w, const float* __restrict__ bias_g,
    float* __restrict__ out) {
  // XCD-bijective swizzle (256 % 8 == 0): a model's 4 blocks -> one XCD
  const int b     = (blockIdx.x & 7) * 32 + (blockIdx.x >> 3);
  const int model = b >> 2;
  const int s     = (b >> 1) & 1;    // sample-tile (rows s*128 ..)
  const int i0    = (b & 1) * BN;    // out-col tile
  const int t     = threadIdx.x;
  const int lane  = t & 63;
  const int wv    = t >> 6;          // 0..15

  __shared__ float w_lds[2][BM][64];   // w quarter-K f32, dbuf
  __shared__ float x_lds[2][BM][64];   // x quarter-K f32, dbuf
  __shared__ int rid[BM];
  __shared__ int wsum[16];

  const float* wbase = w + (size_t)model * (IN_F * OUT_F) + (size_t)i0 * IN_F;
  const int l_r = lane >> 4;         // row within the 4-row group
  const int l_c = lane & 15;         // 16B chunk within the row
#define W_DMA(q, buf)                                                        \
  {                                                                          \
    _Pragma("unroll")                                                        \
    for (int j = 0; j < 2; ++j) {                                            \
      const int r0 = wv * 8 + j * 4;                                         \
      const int rr = r0 + l_r;                                               \
      const float* gs = wbase + (size_t)rr * IN_F + (q) * 64                 \
                        + ((l_c ^ (rr & 7)) << 2);                           \
      dma16(gs, &w_lds[buf][r0][0]);                                         \
    }                                                                        \
  }
  // reg-prefetch of a w quarter (same lane->element mapping as W_DMA)
#define W_REG(q, dst)                                                        \
  {                                                                          \
    _Pragma("unroll")                                                        \
    for (int j = 0; j < 2; ++j) {                                            \
      const int rr = wv * 8 + j * 4 + l_r;                                   \
      dst[j] = *(const float4*)(wbase + (size_t)rr * IN_F + (q) * 64         \
                                + ((l_c ^ (rr & 7)) << 2));                  \
    }                                                                        \
  }

  // ---- idx loads FIRST (scan critical path; in-order vmcnt) ----
  const int4* ip = (const int4*)idxs + t * 2;   // 8 idxs/thread
  int4 iv0 = ip[0], iv1 = ip[1];

  float4 wr2[2], wr3[2];             // w q2/q3 register prefetch
  // s==0 blocks never early-exit: put all w traffic in flight at t0
  if (s == 0) { W_DMA(0, 0) W_DMA(1, 1) W_REG(2, wr2) W_REG(3, wr3) }

  if (t < BM) rid[t] = -1;

  // ---- compaction: thread t owns idxs[8t .. 8t+7] ----
  int cnt = (iv0.x == model) + (iv0.y == model) + (iv0.z == model) + (iv0.w == model)
          + (iv1.x == model) + (iv1.y == model) + (iv1.z == model) + (iv1.w == model);
  int inc = cnt;
#pragma unroll
  for (int d = 1; d < 64; d <<= 1) {
    int u = __shfl_up(inc, d);
    if (lane >= d) inc += u;
  }
  if (lane == 63) wsum[wv] = inc;
  barrier_lds_only();                // RAW-BAR-1: wsum + rid(-1) committed
  int wpre = 0, total = 0;
#pragma unroll
  for (int j = 0; j < 16; ++j) {
    int sj = wsum[j];
    total += sj;
    if (j < wv) wpre += sj;
  }
  const int start = s * BM;
  if (start >= total) return;        // block-uniform (only s==1 can exit;
                                     // those blocks issued no w traffic)
  if (s == 1) { W_DMA(0, 0) W_DMA(1, 1) W_REG(2, wr2) W_REG(3, wr3) }

  int off = wpre + inc - cnt - start;
  {
    int n0 = t * 8;
    if (iv0.x == model) { if ((unsigned)off < BM) rid[off] = n0 + 0; ++off; }
    if (iv0.y == model) { if ((unsigned)off < BM) rid[off] = n0 + 1; ++off; }
    if (iv0.z == model) { if ((unsigned)off < BM) rid[off] = n0 + 2; ++off; }
    if (iv0.w == model) { if ((unsigned)off < BM) rid[off] = n0 + 3; ++off; }
    if (iv1.x == model) { if ((unsigned)off < BM) rid[off] = n0 + 4; ++off; }
    if (iv1.y == model) { if ((unsigned)off < BM) rid[off] = n0 + 5; ++off; }
    if (iv1.z == model) { if ((unsigned)off < BM) rid[off] = n0 + 6; ++off; }
    if (iv1.w == model) { if ((unsigned)off < BM) rid[off] = n0 + 7; ++off; }
  }
  barrier_lds_only();                // RAW-BAR-2: rid ready (vmem untouched)

  // ---- x: per-lane gathered global src, wave-linear LDS dest ----
  // wave wv covers rows [wv*4, wv*4+4) (group 0) and [64+wv*4, ..) (group 1)
  const int   r_0 = wv * 4 + l_r;
  const int   r_1 = 64 + wv * 4 + l_r;
  const int   sr0 = rid[r_0];
  const int   sr1 = rid[r_1];
  const float* xb0 = x + (size_t)(sr0 < 0 ? 0 : sr0) * IN_F
                       + ((l_c ^ (r_0 & 7)) << 2);
  const float* xb1 = x + (size_t)(sr1 < 0 ? 0 : sr1) * IN_F
                       + ((l_c ^ (r_1 & 7)) << 2);
#define X_DMA(q, buf)                                                        \
  {                                                                          \
    dma16(xb0 + (q) * 64, &x_lds[buf][wv * 4][0]);                           \
    dma16(xb1 + (q) * 64, &x_lds[buf][64 + wv * 4][0]);                      \
  }

  X_DMA(0, 0)                        // x q0+q1 in flight immediately
  X_DMA(1, 1)
  float4 xr2[2], xr3[2];             // x q2/q3 register prefetch
  xr2[0] = *(const float4*)(xb0 + 2 * 64);
  xr2[1] = *(const float4*)(xb1 + 2 * 64);
  xr3[0] = *(const float4*)(xb0 + 3 * 64);
  xr3[1] = *(const float4*)(xb1 + 3 * 64);

  // wave tile coords + bias (issued while vmem flies)
  const int wm   = (wv & 3) * 32;    // 4x4 wave grid of 32x32 tiles
  const int wn   = (wv >> 2) * 32;
  const int col  = lane & 15;
  const int quad = lane >> 4;
  float bv[2];
  const float* bp = bias_g + model * OUT_F + i0 + wn + col;
#pragma unroll
  for (int nt = 0; nt < 2; ++nt) bv[nt] = bp[nt * 16];

  __syncthreads();                   // B1: ONLY vmcnt drain = q0,q1 DMA ready

  f32x4 acc[2][2];                   // bias folded into acc init
#pragma unroll
  for (int mt = 0; mt < 2; ++mt)
#pragma unroll
    for (int nt = 0; nt < 2; ++nt)
      acc[mt][nt] = (f32x4){bv[nt], bv[nt], bv[nt], bv[nt]};

  // one quarter = 2 k-steps; A and B frags both f32+XOR-swizzle+pack8
#define MFMA_QUARTER(buf, ks0)                                               \
  {                                                                          \
    _Pragma("unroll")                                                        \
    for (int kk = 0; kk < 2; ++kk) {                                         \
      const int ch0 = kk * 8 + quad * 2;                                     \
      bf16x8 af[2], bfr[2];                                                  \
      _Pragma("unroll")                                                      \
      for (int mt = 0; mt < 2; ++mt) {                                       \
        const int Ra  = wm + mt * 16 + col;                                  \
        const int swa = Ra & 7;                                              \
        float4 a0 = *(const float4*)&x_lds[buf][Ra][((ch0)     ^ swa) << 2]; \
        float4 a1 = *(const float4*)&x_lds[buf][Ra][((ch0 + 1) ^ swa) << 2]; \
        af[mt] = pack8(a0, a1);                                              \
      }                                                                      \
      _Pragma("unroll")                                                      \
      for (int nt = 0; nt < 2; ++nt) {                                       \
        const int R  = wn + nt * 16 + col;                                   \
        const int sw = R & 7;                                                \
        float4 f0 = *(const float4*)&w_lds[buf][R][((ch0)     ^ sw) << 2];   \
        float4 f1 = *(const float4*)&w_lds[buf][R][((ch0 + 1) ^ sw) << 2];   \
        bfr[nt] = pack8(f0, f1);                                             \
      }                                                                      \
      _Pragma("unroll")                                                      \
      for (int mt = 0; mt < 2; ++mt)                                         \
        _Pragma("unroll")                                                    \
        for (int nt = 0; nt < 2; ++nt)                                       \
          acc[mt][nt] = __builtin_amdgcn_mfma_f32_16x16x32_bf16(             \
              af[mt], bfr[nt], acc[mt][nt], 0, 0, 0);                        \
    }                                                                        \
  }

  // write a reg-prefetched quarter into a freed buffer (dest mapping is
  // byte-identical to the DMA's base + lane*16)
#define WX_WRITE(buf, wreg, xreg)                                            \
  {                                                                          \
    _Pragma("unroll")                                                        \
    for (int j = 0; j < 2; ++j) {                                            \
      const int rrw = wv * 8 + j * 4 + l_r;                                  \
      *(float4*)&w_lds[buf][rrw][l_c * 4] = wreg[j];                         \
    }                                                                        \
    *(float4*)&x_lds[buf][r_0][l_c * 4] = xreg[0];                           \
    *(float4*)&x_lds[buf][r_1][l_c * 4] = xreg[1];                           \
  }

  MFMA_QUARTER(0, 0)                 // q0
  barrier_lds_only();                // B2: buf0 reads done (no vmcnt drain)
  WX_WRITE(0, wr2, xr2)              // q2 -> buf0 (regs long since arrived)
  MFMA_QUARTER(1, 2)                 // q1
  barrier_lds_only();                // B3: buf0 writes visible; buf1 free
  WX_WRITE(1, wr3, xr3)              // q3 -> buf1
  MFMA_QUARTER(0, 4)                 // q2
  barrier_lds_only();                // B4: buf1 writes visible
  MFMA_QUARTER(1, 6)                 // q3

  // ---- epilogue: relu + scatter by sample id ----
#pragma unroll
  for (int mt = 0; mt < 2; ++mt) {
#pragma unroll
    for (int reg = 0; reg < 4; ++reg) {
      const int mm = wm + mt * 16 + quad * 4 + reg;   // C/D: row = quad*4+reg
      const int sle = rid[mm];
      if (sle >= 0) {
        float* orow = out + (size_t)sle * OUT_F + i0 + wn + col;
#pragma unroll
        for (int nt = 0; nt < 2; ++nt)
          orow[nt * 16] = fmaxf(acc[mt][nt][reg], 0.0f);
      }
    }
  }
#undef W_DMA
#undef W_REG
#undef X_DMA
#undef MFMA_QUARTER
#undef WX_WRITE
}

extern "C" void kernel_launch(void* const* d_in, const int* in_sizes, int n_in,
                              void* d_out, int out_size, void* d_ws, size_t ws_size,
                              hipStream_t stream) {
  const float* x    = (const float*)d_in[0];
  const int*   idxs = (const int*)d_in[1];
  const float* w    = (const float*)d_in[2];
  const float* b    = (const float*)d_in[3];
  float* out = (float*)d_out;
  (void)d_ws; (void)ws_size;

  fused_kernel<<<N_MODELS * 4, 1024, 0, stream>>>(x, idxs, w, b, out);
}

// Round 11
// 84.277 us; speedup vs baseline: 1.1239x; 1.1147x over previous
//
#include <hip/hip_runtime.h>
#include <stdint.h>

// y[n,i] = relu(b[idx[n],i] + sum_o w[idx[n],i,o] * x[n,o])
// B=8192, 64 models, 256x256 fp32.
//
// R11 = REVERT to R8 (best verified: 83.1us). R9/R10's T14 register-prefetch
// spilled to scratch (WRITE_SIZE 33.6MB, 128B/thread signature) and
// launch_bounds(1024,4) did not change codegen (VGPR stuck at 60) -> per the
// R9 pre-commit, revert. R8 structure:
//  - fused compaction (lgkm-only scan barriers keep DMA in flight),
//  - BOTH streams staged f32 via global_load_lds quarter-K double buffers
//    (w q0+q1 at t0; x q0+q1 right after rid; refills at B2/B3),
//  - A and B MFMA fragments read f32 from LDS with XOR-chunk swizzle +
//    pack8 on the fly,
//  - B1..B4 plain __syncthreads: vmcnt drain == refill-completion guarantee.
// 256 blocks (64 models x 2 sample-tiles x 2 out-tiles), 1024 thr, 16 waves
// 4x4 grid of 32x32 tiles, XCD-bijective swizzle.

#define N_MODELS 64
#define IN_F     256
#define OUT_F    256
#define BATCH    8192
#define BM       128
#define BN       128

typedef __bf16 bf16x8 __attribute__((ext_vector_type(8)));
typedef float  f32x4  __attribute__((ext_vector_type(4)));
typedef __attribute__((address_space(3))) uint32_t lds_u32;
typedef const __attribute__((address_space(1))) uint32_t glb_u32;

__device__ __forceinline__ void dma16(const void* g, void* l) {
  __builtin_amdgcn_global_load_lds((glb_u32*)g, (lds_u32*)l, 16, 0, 0);
}

// raw block barrier that waits LDS ops only -> in-flight DMA survives
__device__ __forceinline__ void barrier_lds_only() {
  asm volatile("s_waitcnt lgkmcnt(0)" ::: "memory");
  __builtin_amdgcn_s_barrier();
  __builtin_amdgcn_sched_barrier(0);
}

__device__ __forceinline__ bf16x8 pack8(float4 a, float4 b) {
  bf16x8 o;                       // native casts -> v_cvt_pk_bf16_f32
  o[0] = (__bf16)a.x; o[1] = (__bf16)a.y; o[2] = (__bf16)a.z; o[3] = (__bf16)a.w;
  o[4] = (__bf16)b.x; o[5] = (__bf16)b.y; o[6] = (__bf16)b.z; o[7] = (__bf16)b.w;
  return o;
}

__global__ __launch_bounds__(1024) void fused_kernel(
    const float* __restrict__ x, const int* __restrict__ idxs,
    const float* __restrict__ w, const float* __restrict__ bias_g,
    float* __restrict__ out) {
  // XCD-bijective swizzle (256 % 8 == 0): a model's 4 blocks -> one XCD
  const int b     = (blockIdx.x & 7) * 32 + (blockIdx.x >> 3);
  const int model = b >> 2;
  const int s     = (b >> 1) & 1;    // sample-tile (rows s*128 ..)
  const int i0    = (b & 1) * BN;    // out-col tile
  const int t     = threadIdx.x;
  const int lane  = t & 63;
  const int wv    = t >> 6;          // 0..15

  __shared__ float w_lds[2][BM][64];   // w quarter-K f32, dbuf, DMA dest
  __shared__ float x_lds[2][BM][64];   // x quarter-K f32, dbuf, DMA dest
  __shared__ int rid[BM];
  __shared__ int wsum[16];

  const float* wbase = w + (size_t)model * (IN_F * OUT_F) + (size_t)i0 * IN_F;
  const int l_r = lane >> 4;         // row within the 4-row group
  const int l_c = lane & 15;         // 16B chunk within the row
#define W_DMA(q, buf)                                                        \
  {                                                                          \
    _Pragma("unroll")                                                        \
    for (int j = 0; j < 2; ++j) {                                            \
      const int r0 = wv * 8 + j * 4;                                         \
      const int rr = r0 + l_r;                                               \
      const float* gs = wbase + (size_t)rr * IN_F + (q) * 64                 \
                        + ((l_c ^ (rr & 7)) << 2);                           \
      dma16(gs, &w_lds[buf][r0][0]);                                         \
    }                                                                        \
  }

  // ---- idx loads FIRST (scan critical path; in-order vmcnt) ----
  const int4* ip = (const int4*)idxs + t * 2;   // 8 idxs/thread
  int4 iv0 = ip[0], iv1 = ip[1];

  // s==0 blocks never early-exit: put w q0+q1 in flight at t0
  if (s == 0) { W_DMA(0, 0) W_DMA(1, 1) }

  if (t < BM) rid[t] = -1;

  // ---- compaction: thread t owns idxs[8t .. 8t+7] ----
  int cnt = (iv0.x == model) + (iv0.y == model) + (iv0.z == model) + (iv0.w == model)
          + (iv1.x == model) + (iv1.y == model) + (iv1.z == model) + (iv1.w == model);
  int inc = cnt;
#pragma unroll
  for (int d = 1; d < 64; d <<= 1) {
    int u = __shfl_up(inc, d);
    if (lane >= d) inc += u;
  }
  if (lane == 63) wsum[wv] = inc;
  barrier_lds_only();                // RAW-BAR-1: wsum + rid(-1) committed
  int wpre = 0, total = 0;
#pragma unroll
  for (int j = 0; j < 16; ++j) {
    int sj = wsum[j];
    total += sj;
    if (j < wv) wpre += sj;
  }
  const int start = s * BM;
  if (start >= total) return;        // block-uniform (only s==1 can exit;
                                     // those blocks issued no DMA)
  if (s == 1) { W_DMA(0, 0) W_DMA(1, 1) }

  int off = wpre + inc - cnt - start;
  {
    int n0 = t * 8;
    if (iv0.x == model) { if ((unsigned)off < BM) rid[off] = n0 + 0; ++off; }
    if (iv0.y == model) { if ((unsigned)off < BM) rid[off] = n0 + 1; ++off; }
    if (iv0.z == model) { if ((unsigned)off < BM) rid[off] = n0 + 2; ++off; }
    if (iv0.w == model) { if ((unsigned)off < BM) rid[off] = n0 + 3; ++off; }
    if (iv1.x == model) { if ((unsigned)off < BM) rid[off] = n0 + 4; ++off; }
    if (iv1.y == model) { if ((unsigned)off < BM) rid[off] = n0 + 5; ++off; }
    if (iv1.z == model) { if ((unsigned)off < BM) rid[off] = n0 + 6; ++off; }
    if (iv1.w == model) { if ((unsigned)off < BM) rid[off] = n0 + 7; ++off; }
  }
  barrier_lds_only();                // RAW-BAR-2: rid ready (DMA untouched)

  // ---- x DMA: per-lane gathered global src, wave-linear LDS dest ----
  // wave wv covers rows [wv*4, wv*4+4) (group 0) and [64+wv*4, ..) (group 1)
  const int   r_0 = wv * 4 + l_r;
  const int   r_1 = 64 + wv * 4 + l_r;
  const int   sr0 = rid[r_0];
  const int   sr1 = rid[r_1];
  const float* xb0 = x + (size_t)(sr0 < 0 ? 0 : sr0) * IN_F
                       + ((l_c ^ (r_0 & 7)) << 2);
  const float* xb1 = x + (size_t)(sr1 < 0 ? 0 : sr1) * IN_F
                       + ((l_c ^ (r_1 & 7)) << 2);
#define X_DMA(q, buf)                                                        \
  {                                                                          \
    dma16(xb0 + (q) * 64, &x_lds[buf][wv * 4][0]);                           \
    dma16(xb1 + (q) * 64, &x_lds[buf][64 + wv * 4][0]);                      \
  }

  X_DMA(0, 0)                        // x q0+q1 in flight immediately
  X_DMA(1, 1)

  // wave tile coords + bias (issued while DMAs fly)
  const int wm   = (wv & 3) * 32;    // 4x4 wave grid of 32x32 tiles
  const int wn   = (wv >> 2) * 32;
  const int col  = lane & 15;
  const int quad = lane >> 4;
  float bv[2];
  const float* bp = bias_g + model * OUT_F + i0 + wn + col;
#pragma unroll
  for (int nt = 0; nt < 2; ++nt) bv[nt] = bp[nt * 16];

  __syncthreads();                   // B1: full drain = all q0,q1 DMA ready

  f32x4 acc[2][2];                   // bias folded into acc init
#pragma unroll
  for (int mt = 0; mt < 2; ++mt)
#pragma unroll
    for (int nt = 0; nt < 2; ++nt)
      acc[mt][nt] = (f32x4){bv[nt], bv[nt], bv[nt], bv[nt]};

  // one quarter = 2 k-steps; A and B frags both f32+XOR-swizzle+pack8
#define MFMA_QUARTER(buf, ks0)                                               \
  {                                                                          \
    _Pragma("unroll")                                                        \
    for (int kk = 0; kk < 2; ++kk) {                                         \
      const int ch0 = kk * 8 + quad * 2;                                     \
      bf16x8 af[2], bfr[2];                                                  \
      _Pragma("unroll")                                                      \
      for (int mt = 0; mt < 2; ++mt) {                                       \
        const int Ra  = wm + mt * 16 + col;                                  \
        const int swa = Ra & 7;                                              \
        float4 a0 = *(const float4*)&x_lds[buf][Ra][((ch0)     ^ swa) << 2]; \
        float4 a1 = *(const float4*)&x_lds[buf][Ra][((ch0 + 1) ^ swa) << 2]; \
        af[mt] = pack8(a0, a1);                                              \
      }                                                                      \
      _Pragma("unroll")                                                      \
      for (int nt = 0; nt < 2; ++nt) {                                       \
        const int R  = wn + nt * 16 + col;                                   \
        const int sw = R & 7;                                                \
        float4 f0 = *(const float4*)&w_lds[buf][R][((ch0)     ^ sw) << 2];   \
        float4 f1 = *(const float4*)&w_lds[buf][R][((ch0 + 1) ^ sw) << 2];   \
        bfr[nt] = pack8(f0, f1);                                             \
      }                                                                      \
      _Pragma("unroll")                                                      \
      for (int mt = 0; mt < 2; ++mt)                                         \
        _Pragma("unroll")                                                    \
        for (int nt = 0; nt < 2; ++nt)                                       \
          acc[mt][nt] = __builtin_amdgcn_mfma_f32_16x16x32_bf16(             \
              af[mt], bfr[nt], acc[mt][nt], 0, 0, 0);                        \
    }                                                                        \
  }

  MFMA_QUARTER(0, 0)                 // q0
  __syncthreads();                   // B2: buf0 reads done
  W_DMA(2, 0) X_DMA(2, 0)            // refill buf0 (overlaps q1 mfma)
  MFMA_QUARTER(1, 2)                 // q1
  __syncthreads();                   // B3: drains q2 DMA; buf1 reads done
  W_DMA(3, 1) X_DMA(3, 1)            // refill buf1 (overlaps q2 mfma)
  MFMA_QUARTER(0, 4)                 // q2
  __syncthreads();                   // B4: drains q3 DMA
  MFMA_QUARTER(1, 6)                 // q3

  // ---- epilogue: relu + scatter by sample id ----
#pragma unroll
  for (int mt = 0; mt < 2; ++mt) {
#pragma unroll
    for (int reg = 0; reg < 4; ++reg) {
      const int mm = wm + mt * 16 + quad * 4 + reg;   // C/D: row = quad*4+reg
      const int sle = rid[mm];
      if (sle >= 0) {
        float* orow = out + (size_t)sle * OUT_F + i0 + wn + col;
#pragma unroll
        for (int nt = 0; nt < 2; ++nt)
          orow[nt * 16] = fmaxf(acc[mt][nt][reg], 0.0f);
      }
    }
  }
#undef W_DMA
#undef X_DMA
#undef MFMA_QUARTER
}

extern "C" void kernel_launch(void* const* d_in, const int* in_sizes, int n_in,
                              void* d_out, int out_size, void* d_ws, size_t ws_size,
                              hipStream_t stream) {
  const float* x    = (const float*)d_in[0];
  const int*   idxs = (const int*)d_in[1];
  const float* w    = (const float*)d_in[2];
  const float* b    = (const float*)d_in[3];
  float* out = (float*)d_out;
  (void)d_ws; (void)ws_size;

  fused_kernel<<<N_MODELS * 4, 1024, 0, stream>>>(x, idxs, w, b, out);
}